// Round 7
// baseline (117.040 us; speedup 1.0000x reference)
//
#include <hip/hip_runtime.h>
#include <math.h>

// Reference: B=256; upsample 64/32/16 -> 256x256 (bilinear, align_corners=True), sum -> maps;
// 5x5 gaussian blur (sigma=4, reflect); per-sample max -> scores.
// d_out: [0:B] scores, [B:] maps (B*256*256).
//
// Lane owns 4 consecutive columns -> one wave covers a full 256-wide row.
//  - rolling separable bilinear per column, LDS-staged inputs (pads ZEROED)
//  - vertical 5-tap in a 4-deep register window; horizontal 5-tap via adjacent-lane shuffles
//  - reflect boundaries via weight folding (no halo sampling)
//  - ALL per-lane 4-wide state is a POD F4 passed BY VALUE (round 6's float[4] lambda
//    params demoted the state to scratch: WRITE_SIZE showed +45 MB of spill traffic)
//  - maps stored once as float4; wave max -> d_ws partials; deterministic reduce kernel
// Pure function of inputs every call (graph-replay safe; no atomics, no init pass).

static constexpr int W     = 256;
static constexpr int QH    = 4;    // blocks per sample
static constexpr int WAVES = 4;    // waves per block
static constexpr int RW    = 16;   // rows owned per wave

struct F4 { float x, y, z, w; };

__device__ __forceinline__ F4 xinterp(const float* __restrict__ buf, int off,
                                      int x0, int x1, int x2, int x3, F4 fx) {
    F4 r; float a, b;
    a = buf[off + x0]; b = buf[off + x0 + 1]; r.x = a + fx.x * (b - a);
    a = buf[off + x1]; b = buf[off + x1 + 1]; r.y = a + fx.y * (b - a);
    a = buf[off + x2]; b = buf[off + x2 + 1]; r.z = a + fx.z * (b - a);
    a = buf[off + x3]; b = buf[off + x3 + 1]; r.w = a + fx.w * (b - a);
    return r;
}

__device__ __forceinline__ F4 lerp3sum(F4 l0, F4 h0, float f0,
                                       F4 l1, F4 h1, float f1,
                                       F4 l2, F4 h2, float f2) {
    F4 r;
    r.x = (l0.x + f0 * (h0.x - l0.x)) + (l1.x + f1 * (h1.x - l1.x)) + (l2.x + f2 * (h2.x - l2.x));
    r.y = (l0.y + f0 * (h0.y - l0.y)) + (l1.y + f1 * (h1.y - l1.y)) + (l2.y + f2 * (h2.y - l2.y));
    r.z = (l0.z + f0 * (h0.z - l0.z)) + (l1.z + f1 * (h1.z - l1.z)) + (l2.z + f2 * (h2.z - l2.z));
    r.w = (l0.w + f0 * (h0.w - l0.w)) + (l1.w + f1 * (h1.w - l1.w)) + (l2.w + f2 * (h2.w - l2.w));
    return r;
}

// wb*(a+e) + wa*(b+d) + wc*c  (interior vertical 5-tap)
__device__ __forceinline__ F4 vtap5(F4 a, F4 b, F4 c, F4 d, F4 e,
                                    float wb_, float wa_, float wc_) {
    F4 r;
    r.x = wb_ * (a.x + e.x) + wa_ * (b.x + d.x) + wc_ * c.x;
    r.y = wb_ * (a.y + e.y) + wa_ * (b.y + d.y) + wc_ * c.y;
    r.z = wb_ * (a.z + e.z) + wa_ * (b.z + d.z) + wc_ * c.z;
    r.w = wb_ * (a.w + e.w) + wa_ * (b.w + d.w) + wc_ * c.w;
    return r;
}

// w0*a + w1*b + w2*c + w3*d  (boundary-folded vertical taps)
__device__ __forceinline__ F4 wsum4(float w0, F4 a, float w1, F4 b,
                                    float w2, F4 c, float w3, F4 d) {
    F4 r;
    r.x = w0 * a.x + w1 * b.x + w2 * c.x + w3 * d.x;
    r.y = w0 * a.y + w1 * b.y + w2 * c.y + w3 * d.y;
    r.z = w0 * a.z + w1 * b.z + w2 * c.z + w3 * d.z;
    r.w = w0 * a.w + w1 * b.w + w2 * c.w + w3 * d.w;
    return r;
}

__global__ __launch_bounds__(256, 4) void fused_kernel(
    const float* __restrict__ in0,   // [B,64,64]
    const float* __restrict__ in1,   // [B,32,32]
    const float* __restrict__ in2,   // [B,16,16]
    float* __restrict__ part,        // [B*QH*WAVES]
    float* __restrict__ maps)        // [B,256,256]
{
    const int t    = threadIdx.x;
    const int lane = t & 63;
    const int w    = t >> 6;
    const int bid  = blockIdx.x;
    const int b    = bid >> 2;
    const int R0   = (bid & 3) * (WAVES * RW) + w * RW;   // first owned row

    // Padded so x+1 / y+1 reads at the fx==0 / fy==0 edge stay in-bounds; pads zeroed.
    __shared__ float s0[64 * 64 + 68];
    __shared__ float s1[32 * 32 + 36];
    __shared__ float s2[16 * 16 + 20];

    {
        const float4* g0 = (const float4*)(in0 + (size_t)b * 4096);
        const float4* g1 = (const float4*)(in1 + (size_t)b * 1024);
        float4* l0 = (float4*)s0;
#pragma unroll
        for (int i = 0; i < 4; ++i) l0[t + i * 256] = g0[t + i * 256];
        ((float4*)s1)[t] = g1[t];
        if (t < 64) ((float4*)s2)[t] = ((const float4*)(in2 + (size_t)b * 256))[t];
        if (t < 68) s0[64 * 64 + t] = 0.0f;
        if (t < 36) s1[32 * 32 + t] = 0.0f;
        if (t < 20) s2[16 * 16 + t] = 0.0f;
    }
    __syncthreads();

    const float inv255 = 1.0f / 255.0f;

    // ---- per-column x params; lane owns cols c = 4*lane + j ----
    int xA0, xB0, xC0, xD0, xA1, xB1, xC1, xD1, xA2, xB2, xC2, xD2;
    F4 fx0, fx1, fx2;
    {
        int c = 4 * lane, ix, x0;
        ix = (c + 0) * 63; x0 = ix / 255; fx0.x = (float)(ix - 255 * x0) * inv255; xA0 = x0;
        ix = (c + 1) * 63; x0 = ix / 255; fx0.y = (float)(ix - 255 * x0) * inv255; xB0 = x0;
        ix = (c + 2) * 63; x0 = ix / 255; fx0.z = (float)(ix - 255 * x0) * inv255; xC0 = x0;
        ix = (c + 3) * 63; x0 = ix / 255; fx0.w = (float)(ix - 255 * x0) * inv255; xD0 = x0;
        ix = (c + 0) * 31; x0 = ix / 255; fx1.x = (float)(ix - 255 * x0) * inv255; xA1 = x0;
        ix = (c + 1) * 31; x0 = ix / 255; fx1.y = (float)(ix - 255 * x0) * inv255; xB1 = x0;
        ix = (c + 2) * 31; x0 = ix / 255; fx1.z = (float)(ix - 255 * x0) * inv255; xC1 = x0;
        ix = (c + 3) * 31; x0 = ix / 255; fx1.w = (float)(ix - 255 * x0) * inv255; xD1 = x0;
        ix = (c + 0) * 15; x0 = ix / 255; fx2.x = (float)(ix - 255 * x0) * inv255; xA2 = x0;
        ix = (c + 1) * 15; x0 = ix / 255; fx2.y = (float)(ix - 255 * x0) * inv255; xB2 = x0;
        ix = (c + 2) * 15; x0 = ix / 255; fx2.z = (float)(ix - 255 * x0) * inv255; xC2 = x0;
        ix = (c + 3) * 15; x0 = ix / 255; fx2.w = (float)(ix - 255 * x0) * inv255; xD2 = x0;
    }

    // ---- gaussian weights (ksize=5, sigma=4) ----
    const float e1  = expf(-1.0f / 32.0f);
    const float e2  = expf(-4.0f / 32.0f);
    const float nrm = 1.0f + 2.0f * e1 + 2.0f * e2;
    const float wc = 1.0f / nrm, wa = e1 / nrm, wb = e2 / nrm;

    // ---- rolling bilinear state from row rs ----
    const int rs = max(R0 - 2, 0);
    const int re = min(R0 + RW + 1, 255);
    int ya, yb, yc, ra, rb, rc;
    {
        int iy;
        iy = rs * 63; ya = iy / 255; ra = iy - 255 * ya;
        iy = rs * 31; yb = iy / 255; rb = iy - 255 * yb;
        iy = rs * 15; yc = iy / 255; rc = iy - 255 * yc;
    }
    F4 lo0 = xinterp(s0, ya * 64,      xA0, xB0, xC0, xD0, fx0);
    F4 hi0 = xinterp(s0, ya * 64 + 64, xA0, xB0, xC0, xD0, fx0);
    F4 lo1 = xinterp(s1, yb * 32,      xA1, xB1, xC1, xD1, fx1);
    F4 hi1 = xinterp(s1, yb * 32 + 32, xA1, xB1, xC1, xD1, fx1);
    F4 lo2 = xinterp(s2, yc * 16,      xA2, xB2, xC2, xD2, fx2);
    F4 hi2 = xinterp(s2, yc * 16 + 16, xA2, xB2, xC2, xD2, fx2);

    F4 m0, m1, m2, m3, mn;
    float gmax = -INFINITY;

    // produce next map row, advance rolling state (wave-uniform branches)
    auto roll = [&]() -> F4 {
        F4 out = lerp3sum(lo0, hi0, (float)ra * inv255,
                          lo1, hi1, (float)rb * inv255,
                          lo2, hi2, (float)rc * inv255);
        ra += 63;
        if (ra >= 255) { ra -= 255; ++ya; lo0 = hi0; hi0 = xinterp(s0, (ya + 1) * 64, xA0, xB0, xC0, xD0, fx0); }
        rb += 31;
        if (rb >= 255) { rb -= 255; ++yb; lo1 = hi1; hi1 = xinterp(s1, (yb + 1) * 32, xA1, xB1, xC1, xD1, fx1); }
        rc += 15;
        if (rc >= 255) { rc -= 255; ++yc; lo2 = hi2; hi2 = xinterp(s2, (yc + 1) * 16, xA2, xB2, xC2, xD2, fx2); }
        return out;
    };

    // horizontal 5-tap (reflect at x edges via fold) + running max
    auto hmax = [&](F4 vv) {
        float l1 = __shfl_up(vv.w, 1);    // col-1
        float l2 = __shfl_up(vv.z, 1);    // col-2
        float r1 = __shfl_down(vv.x, 1);  // col+4
        float r2 = __shfl_down(vv.y, 1);  // col+5
        if (lane == 0)  { l1 = vv.y; l2 = vv.z; }
        if (lane == 63) { r1 = vv.z; r2 = vv.y; }
        float o0 = wc * vv.x + wa * (l1 + vv.y)   + wb * (l2 + vv.z);
        float o1 = wc * vv.y + wa * (vv.x + vv.z) + wb * (l1 + vv.w);
        float o2 = wc * vv.z + wa * (vv.y + vv.w) + wb * (vv.x + r1);
        float o3 = wc * vv.w + wa * (vv.z + r1)   + wb * (vv.y + r2);
        gmax = fmaxf(gmax, fmaxf(fmaxf(o0, o1), fmaxf(o2, o3)));
    };

    float* __restrict__ mrow = maps + (size_t)b * W * W + 4 * lane;
    auto store_row = [&](int r, F4 v) {
        *(float4*)(mrow + (size_t)r * W) = make_float4(v.x, v.y, v.z, v.w);
    };

    // ---- prologue: prime window with rows rs..rs+3 ----
    m0 = roll(); m1 = roll(); m2 = roll(); m3 = roll();
    if (R0 == 0) {
        store_row(0, m0); store_row(1, m1); store_row(2, m2); store_row(3, m3);
        hmax(wsum4(wc, m0, 2.0f * wa, m1, 2.0f * wb, m2, 0.0f, m3));        // out row 0
        hmax(wsum4(wa, m0, wc + wb, m1, wa, m2, wb, m3));                   // out row 1
    } else {
        store_row(R0, m2); store_row(R0 + 1, m3);
    }

    // ---- main loop: store + blur ----
    for (int rn = rs + 4; rn <= R0 + RW - 1; ++rn) {
        mn = roll();
        store_row(rn, mn);
        hmax(vtap5(m0, m1, m2, m3, mn, wb, wa, wc));
        m0 = m1; m1 = m2; m2 = m3; m3 = mn;
    }
    // ---- vertical-halo rows (no store) ----
    for (int rn = R0 + RW; rn <= re; ++rn) {
        mn = roll();
        hmax(vtap5(m0, m1, m2, m3, mn, wb, wa, wc));
        m0 = m1; m1 = m2; m2 = m3; m3 = mn;
    }
    if (R0 == W - RW) {                              // bottom folds (window = rows 252..255)
        hmax(wsum4(wb, m0, wa, m1, wc + wb, m2, wa, m3));                   // out row 254
        hmax(wsum4(0.0f, m0, 2.0f * wb, m1, 2.0f * wa, m2, wc, m3));        // out row 255
    }

    // ---- wave max -> partial ----
#pragma unroll
    for (int off = 32; off > 0; off >>= 1)
        gmax = fmaxf(gmax, __shfl_down(gmax, off));
    if (lane == 0) part[bid * WAVES + w] = gmax;
}

__global__ void reduce_kernel(const float* __restrict__ part,
                              float* __restrict__ scores, int B) {
    int i = blockIdx.x * blockDim.x + threadIdx.x;
    if (i < B) {
        const int P = QH * WAVES;   // 16 consecutive partials per sample
        float m = part[P * i];
#pragma unroll
        for (int k = 1; k < P; ++k) m = fmaxf(m, part[P * i + k]);
        scores[i] = m;
    }
}

extern "C" void kernel_launch(void* const* d_in, const int* in_sizes, int n_in,
                              void* d_out, int out_size, void* d_ws, size_t ws_size,
                              hipStream_t stream) {
    const float* in0 = (const float*)d_in[0];
    const float* in1 = (const float*)d_in[1];
    const float* in2 = (const float*)d_in[2];
    const int B = in_sizes[0] / (64 * 64);

    float* scores = (float*)d_out;
    float* maps   = (float*)d_out + B;
    float* part   = (float*)d_ws;           // B*16 floats, fully rewritten each call

    hipLaunchKernelGGL(fused_kernel, dim3(B * QH), dim3(256), 0, stream,
                       in0, in1, in2, part, maps);
    hipLaunchKernelGGL(reduce_kernel, dim3((B + 255) / 256), dim3(256), 0, stream,
                       part, scores, B);
}